// Round 2
// baseline (718.846 us; speedup 1.0000x reference)
//
#include <hip/hip_runtime.h>

// MSTGCN block, MI355X. Structure:
//  1. edge pass: deg (atomic), per-dest counts + positions (atomic)
//  2. single-block exclusive scan -> CSR rowptr
//  3. fill CSR (src, edge weight w = -dinv[row]*dinv[col])
//  4. prop gather kernel x -> P1, P1 -> P2  (no atomics, float4 per lane)
//  5. weight-prep: Wa=W0-W2, Wb=W1, Wc=2*W2 ; transpose time_W/res_W for lane-coalesced reads
//  6. fused wave-per-(b,n): cheb einsum + relu + time conv + res conv + relu + LN + transpose

#define F_IN 32
#define TT   16
#define CCH  64
#define FTN  512  // F_IN*TT floats per (b,n)

__global__ void k_edge1(const int* __restrict__ row, const int* __restrict__ col,
                        float* __restrict__ deg, int* __restrict__ cnt,
                        int* __restrict__ pos, int E) {
    int i = blockIdx.x * 256 + threadIdx.x;
    if (i < E) {
        atomicAdd(&deg[row[i]], 1.0f);
        pos[i] = atomicAdd(&cnt[col[i]], 1);
    }
}

__global__ void k_scan(const int* __restrict__ cnt, int* __restrict__ rowptr, int n) {
    __shared__ int sdata[1024];
    int tid = threadIdx.x;
    int run = 0;
    for (int base = 0; base < n; base += 1024) {
        int v = (base + tid < n) ? cnt[base + tid] : 0;
        sdata[tid] = v;
        __syncthreads();
        for (int off = 1; off < 1024; off <<= 1) {
            int add = (tid >= off) ? sdata[tid - off] : 0;
            __syncthreads();
            sdata[tid] += add;
            __syncthreads();
        }
        int incl  = sdata[tid];
        int total = sdata[1023];
        if (base + tid < n) rowptr[base + tid] = run + incl - v;
        run += total;
        __syncthreads();   // protect sdata before next chunk overwrites
    }
    if (tid == 0) rowptr[n] = run;
}

__global__ void k_fill(const int* __restrict__ row, const int* __restrict__ col,
                       const float* __restrict__ deg, const int* __restrict__ rowptr,
                       const int* __restrict__ pos, int* __restrict__ srcs,
                       float* __restrict__ wsort, int E) {
    int i = blockIdx.x * 256 + threadIdx.x;
    if (i < E) {
        int r = row[i], c = col[i];
        float dr = deg[r], dc = deg[c];
        float w = 0.0f;
        if (dr > 0.0f && dc > 0.0f) w = -(rsqrtf(dr) * rsqrtf(dc));
        int slot = rowptr[c] + pos[i];
        srcs[slot]  = r;
        wsort[slot] = w;
    }
}

// Gather prop: one block per destination node. 256 threads x float4 = the full
// B*F*T = 1024 floats of one source row per iteration. No atomics; accumulation
// order fixed by CSR order.
__global__ void k_prop(const float* __restrict__ zin, float* __restrict__ zout,
                       const int* __restrict__ rowptr, const int* __restrict__ srcs,
                       const float* __restrict__ wsort, int N) {
    int n   = blockIdx.x;
    int tid = threadIdx.x;                 // 0..255
    int beg = rowptr[n], end = rowptr[n + 1];
    const size_t bstride = (size_t)N * FTN;
    // thread-private element offset: first 128 threads cover b=0, rest b=1
    const size_t eoff = (size_t)(tid >> 7) * bstride + (size_t)(tid & 127) * 4;

    float4 a = make_float4(0.f, 0.f, 0.f, 0.f);
    int j = beg;
    for (; j + 1 < end; j += 2) {
        int   s0 = srcs[j],  s1 = srcs[j + 1];
        float w0 = wsort[j], w1 = wsort[j + 1];
        float4 v0 = *reinterpret_cast<const float4*>(zin + (size_t)s0 * FTN + eoff);
        float4 v1 = *reinterpret_cast<const float4*>(zin + (size_t)s1 * FTN + eoff);
        a.x = fmaf(w0, v0.x, fmaf(w1, v1.x, a.x));
        a.y = fmaf(w0, v0.y, fmaf(w1, v1.y, a.y));
        a.z = fmaf(w0, v0.z, fmaf(w1, v1.z, a.z));
        a.w = fmaf(w0, v0.w, fmaf(w1, v1.w, a.w));
    }
    if (j < end) {
        int   s0 = srcs[j];
        float w0 = wsort[j];
        float4 v0 = *reinterpret_cast<const float4*>(zin + (size_t)s0 * FTN + eoff);
        a.x = fmaf(w0, v0.x, a.x);
        a.y = fmaf(w0, v0.y, a.y);
        a.z = fmaf(w0, v0.z, a.z);
        a.w = fmaf(w0, v0.w, a.w);
    }
    *reinterpret_cast<float4*>(zout + (size_t)n * FTN + eoff) = a;
}

// Weight prep: Wabc[3][32][64] (f,co), tWt[64][3][64] (ci,dt,co), rWt[32][64] (f,co)
__global__ void k_prep(const float* __restrict__ cheb_W, const float* __restrict__ time_W,
                       const float* __restrict__ res_W,
                       float* __restrict__ Wabc, float* __restrict__ tWt, float* __restrict__ rWt) {
    int i = blockIdx.x * 256 + threadIdx.x;
    if (i < F_IN * 64) {
        int f = i >> 6, o = i & 63;
        float w0 = cheb_W[(0 * F_IN + f) * 64 + o];
        float w1 = cheb_W[(1 * F_IN + f) * 64 + o];
        float w2 = cheb_W[(2 * F_IN + f) * 64 + o];
        Wabc[i]          = w0 - w2;
        Wabc[2048 + i]   = w1;
        Wabc[4096 + i]   = 2.0f * w2;
        rWt[i] = res_W[o * F_IN + f];
    }
    if (i < 64 * 3 * 64) {
        int ci = i / 192, r = i % 192, dt = r >> 6, co = r & 63;
        tWt[i] = time_W[(co * 64 + ci) * 3 + dt];
    }
}

// Fused per-(b,n) kernel. 512 threads = 8 waves; each wave owns one item (b,n).
// lane = output channel (64 = wave size). 16 time-steps in registers.
__global__ __launch_bounds__(512, 2) void k_fused(
        const float* __restrict__ x, const float* __restrict__ P1, const float* __restrict__ P2,
        const float* __restrict__ Wabc, const float* __restrict__ rWt, const float* __restrict__ tWt,
        const float* __restrict__ cheb_b, const float* __restrict__ time_b,
        const float* __restrict__ res_b, const float* __restrict__ ln_g,
        const float* __restrict__ ln_b, float* __restrict__ out, int N) {
    __shared__ float sgp[8][64][20];   // per-wave sg tile, stride 20 (halo t=-1,16 + b128 align)
    int lane = threadIdx.x & 63;
    int wib  = threadIdx.x >> 6;
    int co   = lane;
    float chb = cheb_b[co], tb = time_b[co], rb = res_b[co];
    float g   = ln_g[co],   bb = ln_b[co];
    float (*sg)[20] = sgp[wib];

    int gw = blockIdx.x * 8 + wib;
    int nw = gridDim.x * 8;
    int nitems = 2 * N;
    const size_t bstride = (size_t)N * FTN;

    for (int item = gw; item < nitems; item += nw) {
        int b = (item >= N) ? 1 : 0;
        int n = item - b * N;
        const float4* x4 = reinterpret_cast<const float4*>(x  + b * bstride + (size_t)n * FTN);
        const float4* a4 = reinterpret_cast<const float4*>(P1 + b * bstride + (size_t)n * FTN);
        const float4* b4 = reinterpret_cast<const float4*>(P2 + b * bstride + (size_t)n * FTN);

        float acc[16], res[16];
#pragma unroll
        for (int t = 0; t < 16; ++t) { acc[t] = chb; res[t] = rb; }

        // phase 1: cheb einsum (3 mats, Tx2 folded) + residual 1x1, contraction over f
        for (int f = 0; f < F_IN; ++f) {
            float wa = Wabc[f * 64 + co];
            float wb = Wabc[2048 + f * 64 + co];
            float wc = Wabc[4096 + f * 64 + co];
            float wr = rWt[f * 64 + co];
#pragma unroll
            for (int q = 0; q < 4; ++q) {
                float4 xv = x4[f * 4 + q];
                float4 av = a4[f * 4 + q];
                float4 bv = b4[f * 4 + q];
                acc[q*4+0] = fmaf(wa, xv.x, fmaf(wb, av.x, fmaf(wc, bv.x, acc[q*4+0])));
                acc[q*4+1] = fmaf(wa, xv.y, fmaf(wb, av.y, fmaf(wc, bv.y, acc[q*4+1])));
                acc[q*4+2] = fmaf(wa, xv.z, fmaf(wb, av.z, fmaf(wc, bv.z, acc[q*4+2])));
                acc[q*4+3] = fmaf(wa, xv.w, fmaf(wb, av.w, fmaf(wc, bv.w, acc[q*4+3])));
                res[q*4+0] = fmaf(wr, xv.x, res[q*4+0]);
                res[q*4+1] = fmaf(wr, xv.y, res[q*4+1]);
                res[q*4+2] = fmaf(wr, xv.z, res[q*4+2]);
                res[q*4+3] = fmaf(wr, xv.w, res[q*4+3]);
            }
        }

        // relu -> sg tile in LDS (wave-private; same-wave DS ops are ordered, no barrier)
        sg[co][0] = 0.f; sg[co][17] = 0.f; sg[co][18] = 0.f; sg[co][19] = 0.f;
#pragma unroll
        for (int t = 0; t < 16; ++t) sg[co][t + 1] = fmaxf(acc[t], 0.f);

        // phase 2: temporal conv (kernel 3, pad 1), contraction over ci (broadcast LDS reads)
#pragma unroll
        for (int t = 0; t < 16; ++t) acc[t] = res[t] + tb;
        for (int ci = 0; ci < 64; ++ci) {
            float w0 = tWt[ci * 192 + co];
            float w1 = tWt[ci * 192 + 64 + co];
            float w2 = tWt[ci * 192 + 128 + co];
            const float4* srow = reinterpret_cast<const float4*>(sg[ci]);
            float4 s0 = srow[0], s1 = srow[1], s2 = srow[2], s3 = srow[3], s4 = srow[4];
            float s[20] = { s0.x,s0.y,s0.z,s0.w, s1.x,s1.y,s1.z,s1.w,
                            s2.x,s2.y,s2.z,s2.w, s3.x,s3.y,s3.z,s3.w,
                            s4.x,s4.y,s4.z,s4.w };
#pragma unroll
            for (int t = 0; t < 16; ++t)
                acc[t] = fmaf(w0, s[t], fmaf(w1, s[t + 1], fmaf(w2, s[t + 2], acc[t])));
        }

        // relu + LayerNorm over channels (64 = wave), write transposed (b,n,co,t)
        float z[16];
#pragma unroll
        for (int t = 0; t < 16; ++t) {
            float zz = fmaxf(acc[t], 0.f);
            float s1 = zz, s2 = zz * zz;
#pragma unroll
            for (int off = 32; off >= 1; off >>= 1) {
                s1 += __shfl_xor(s1, off);
                s2 += __shfl_xor(s2, off);
            }
            float mu  = s1 * (1.0f / 64.0f);
            float var = s2 * (1.0f / 64.0f) - mu * mu;
            z[t] = (zz - mu) * rsqrtf(var + 1e-5f) * g + bb;
        }
        float4* o4 = reinterpret_cast<float4*>(out + (size_t)item * 1024 + co * 16);
        o4[0] = make_float4(z[0],  z[1],  z[2],  z[3]);
        o4[1] = make_float4(z[4],  z[5],  z[6],  z[7]);
        o4[2] = make_float4(z[8],  z[9],  z[10], z[11]);
        o4[3] = make_float4(z[12], z[13], z[14], z[15]);
    }
}

extern "C" void kernel_launch(void* const* d_in, const int* in_sizes, int n_in,
                              void* d_out, int out_size, void* d_ws, size_t ws_size,
                              hipStream_t stream) {
    const float* x      = (const float*)d_in[0];
    const int*   ei     = (const int*)d_in[1];
    const float* cheb_W = (const float*)d_in[2];
    const float* cheb_b = (const float*)d_in[3];
    const float* time_W = (const float*)d_in[4];
    const float* time_b = (const float*)d_in[5];
    const float* res_W  = (const float*)d_in[6];
    const float* res_b  = (const float*)d_in[7];
    const float* ln_g   = (const float*)d_in[8];
    const float* ln_b   = (const float*)d_in[9];
    float* out = (float*)d_out;

    const int N = in_sizes[0] / (2 * F_IN * TT);   // B=2
    const int E = in_sizes[1] / 2;
    const int* row = ei;
    const int* col = ei + E;

    // workspace carve-out (256B aligned)
    char* w = (char*)d_ws;
    size_t off = 0;
    auto carve = [&](size_t bytes) { off = (off + 255) & ~(size_t)255; size_t o = off; off += bytes; return o; };
    float* deg    = (float*)(w + carve((size_t)N * 4));
    int*   cnt    = (int*)  (w + carve((size_t)N * 4));
    int*   rowptr = (int*)  (w + carve((size_t)(N + 1) * 4));
    int*   pos    = (int*)  (w + carve((size_t)E * 4));
    int*   srcs   = (int*)  (w + carve((size_t)E * 4));
    float* wsort  = (float*)(w + carve((size_t)E * 4));
    float* Wabc   = (float*)(w + carve(3 * 32 * 64 * 4));
    float* tWt    = (float*)(w + carve(64 * 3 * 64 * 4));
    float* rWt    = (float*)(w + carve(32 * 64 * 4));
    float* P1     = (float*)(w + carve((size_t)2 * N * FTN * 4));
    float* P2     = (float*)(w + carve((size_t)2 * N * FTN * 4));
    (void)ws_size; (void)n_in; (void)out_size;

    hipMemsetAsync(deg, 0, (size_t)N * 4, stream);
    hipMemsetAsync(cnt, 0, (size_t)N * 4, stream);

    int eb = (E + 255) / 256;
    k_edge1<<<eb, 256, 0, stream>>>(row, col, deg, cnt, pos, E);
    k_scan<<<1, 1024, 0, stream>>>(cnt, rowptr, N);
    k_fill<<<eb, 256, 0, stream>>>(row, col, deg, rowptr, pos, srcs, wsort, E);
    k_prop<<<N, 256, 0, stream>>>(x,  P1, rowptr, srcs, wsort, N);
    k_prop<<<N, 256, 0, stream>>>(P1, P2, rowptr, srcs, wsort, N);
    k_prep<<<48, 256, 0, stream>>>(cheb_W, time_W, res_W, Wabc, tWt, rWt);

    int items  = 2 * N;
    int blocks = (items + 7) / 8;   // 8 waves/block, 1 item/wave
    k_fused<<<blocks, 512, 0, stream>>>(x, P1, P2, Wabc, rWt, tWt,
                                        cheb_b, time_b, res_b, ln_g, ln_b, out, N);
}

// Round 3
// 650.033 us; speedup vs baseline: 1.1059x; 1.1059x over previous
//
#include <hip/hip_runtime.h>

// MSTGCN block, MI355X. Structure:
//  1. edge pass: deg (atomic), per-dest counts + positions (atomic)
//  2. single-block exclusive scan -> CSR rowptr
//  3. fill CSR (src, edge weight w = -dinv[row]*dinv[col])
//  4. prop gather kernel x -> P1, P1 -> P2  (no atomics, float4 per lane)
//  5. weight-prep: Wa=W0-W2, Wb=W1, Wc=2*W2 ; transpose time_W/res_W for lane-coalesced reads
//  6. fused wave-per-(b,n): cheb einsum + relu + time conv + res conv + relu + LN + transpose
//     R2: 256-thread blocks (4 waves, 20KB LDS) — was 512/40KB, occupancy-capped at 24%.

#define F_IN 32
#define TT   16
#define CCH  64
#define FTN  512  // F_IN*TT floats per (b,n)
#define WPB  4    // waves per block in k_fused

__global__ void k_edge1(const int* __restrict__ row, const int* __restrict__ col,
                        float* __restrict__ deg, int* __restrict__ cnt,
                        int* __restrict__ pos, int E) {
    int i = blockIdx.x * 256 + threadIdx.x;
    if (i < E) {
        atomicAdd(&deg[row[i]], 1.0f);
        pos[i] = atomicAdd(&cnt[col[i]], 1);
    }
}

__global__ void k_scan(const int* __restrict__ cnt, int* __restrict__ rowptr, int n) {
    __shared__ int sdata[1024];
    int tid = threadIdx.x;
    int run = 0;
    for (int base = 0; base < n; base += 1024) {
        int v = (base + tid < n) ? cnt[base + tid] : 0;
        sdata[tid] = v;
        __syncthreads();
        for (int off = 1; off < 1024; off <<= 1) {
            int add = (tid >= off) ? sdata[tid - off] : 0;
            __syncthreads();
            sdata[tid] += add;
            __syncthreads();
        }
        int incl  = sdata[tid];
        int total = sdata[1023];
        if (base + tid < n) rowptr[base + tid] = run + incl - v;
        run += total;
        __syncthreads();   // protect sdata before next chunk overwrites
    }
    if (tid == 0) rowptr[n] = run;
}

__global__ void k_fill(const int* __restrict__ row, const int* __restrict__ col,
                       const float* __restrict__ deg, const int* __restrict__ rowptr,
                       const int* __restrict__ pos, int* __restrict__ srcs,
                       float* __restrict__ wsort, int E) {
    int i = blockIdx.x * 256 + threadIdx.x;
    if (i < E) {
        int r = row[i], c = col[i];
        float dr = deg[r], dc = deg[c];
        float w = 0.0f;
        if (dr > 0.0f && dc > 0.0f) w = -(rsqrtf(dr) * rsqrtf(dc));
        int slot = rowptr[c] + pos[i];
        srcs[slot]  = r;
        wsort[slot] = w;
    }
}

// Gather prop: one block per destination node. 256 threads x float4 = the full
// B*F*T = 1024 floats of one source row per iteration. No atomics.
__global__ void k_prop(const float* __restrict__ zin, float* __restrict__ zout,
                       const int* __restrict__ rowptr, const int* __restrict__ srcs,
                       const float* __restrict__ wsort, int N) {
    int n   = blockIdx.x;
    int tid = threadIdx.x;                 // 0..255
    int beg = rowptr[n], end = rowptr[n + 1];
    const size_t bstride = (size_t)N * FTN;
    const size_t eoff = (size_t)(tid >> 7) * bstride + (size_t)(tid & 127) * 4;

    float4 a = make_float4(0.f, 0.f, 0.f, 0.f);
    int j = beg;
    for (; j + 1 < end; j += 2) {
        int   s0 = srcs[j],  s1 = srcs[j + 1];
        float w0 = wsort[j], w1 = wsort[j + 1];
        float4 v0 = *reinterpret_cast<const float4*>(zin + (size_t)s0 * FTN + eoff);
        float4 v1 = *reinterpret_cast<const float4*>(zin + (size_t)s1 * FTN + eoff);
        a.x = fmaf(w0, v0.x, fmaf(w1, v1.x, a.x));
        a.y = fmaf(w0, v0.y, fmaf(w1, v1.y, a.y));
        a.z = fmaf(w0, v0.z, fmaf(w1, v1.z, a.z));
        a.w = fmaf(w0, v0.w, fmaf(w1, v1.w, a.w));
    }
    if (j < end) {
        int   s0 = srcs[j];
        float w0 = wsort[j];
        float4 v0 = *reinterpret_cast<const float4*>(zin + (size_t)s0 * FTN + eoff);
        a.x = fmaf(w0, v0.x, a.x);
        a.y = fmaf(w0, v0.y, a.y);
        a.z = fmaf(w0, v0.z, a.z);
        a.w = fmaf(w0, v0.w, a.w);
    }
    *reinterpret_cast<float4*>(zout + (size_t)n * FTN + eoff) = a;
}

// Weight prep: Wabc[3][32][64] (f,co), tWt[64][3][64] (ci,dt,co), rWt[32][64] (f,co)
__global__ void k_prep(const float* __restrict__ cheb_W, const float* __restrict__ time_W,
                       const float* __restrict__ res_W,
                       float* __restrict__ Wabc, float* __restrict__ tWt, float* __restrict__ rWt) {
    int i = blockIdx.x * 256 + threadIdx.x;
    if (i < F_IN * 64) {
        int f = i >> 6, o = i & 63;
        float w0 = cheb_W[(0 * F_IN + f) * 64 + o];
        float w1 = cheb_W[(1 * F_IN + f) * 64 + o];
        float w2 = cheb_W[(2 * F_IN + f) * 64 + o];
        Wabc[i]          = w0 - w2;
        Wabc[2048 + i]   = w1;
        Wabc[4096 + i]   = 2.0f * w2;
        rWt[i] = res_W[o * F_IN + f];
    }
    if (i < 64 * 3 * 64) {
        int ci = i / 192, r = i % 192, dt = r >> 6, co = r & 63;
        tWt[i] = time_W[(co * 64 + ci) * 3 + dt];
    }
}

// Fused per-(b,n) kernel. 256 threads = 4 waves; each wave owns one item (b,n).
// lane = output channel (64 = wave size). 16 time-steps in registers.
__global__ __launch_bounds__(256) void k_fused(
        const float* __restrict__ x, const float* __restrict__ P1, const float* __restrict__ P2,
        const float* __restrict__ Wabc, const float* __restrict__ rWt, const float* __restrict__ tWt,
        const float* __restrict__ cheb_b, const float* __restrict__ time_b,
        const float* __restrict__ res_b, const float* __restrict__ ln_g,
        const float* __restrict__ ln_b, float* __restrict__ out, int N) {
    __shared__ float sgp[WPB][64][20];   // per-wave sg tile, stride 20 (halo t=-1,16 + b128 align)
    int lane = threadIdx.x & 63;
    int wib  = threadIdx.x >> 6;
    int co   = lane;
    float chb = cheb_b[co], tb = time_b[co], rb = res_b[co];
    float g   = ln_g[co],   bb = ln_b[co];
    float (*sg)[20] = sgp[wib];

    int gw = blockIdx.x * WPB + wib;
    int nw = gridDim.x * WPB;
    int nitems = 2 * N;
    const size_t bstride = (size_t)N * FTN;

    for (int item = gw; item < nitems; item += nw) {
        int b = (item >= N) ? 1 : 0;
        int n = item - b * N;
        const float4* x4 = reinterpret_cast<const float4*>(x  + b * bstride + (size_t)n * FTN);
        const float4* a4 = reinterpret_cast<const float4*>(P1 + b * bstride + (size_t)n * FTN);
        const float4* b4 = reinterpret_cast<const float4*>(P2 + b * bstride + (size_t)n * FTN);

        float acc[16], res[16];
#pragma unroll
        for (int t = 0; t < 16; ++t) { acc[t] = chb; res[t] = rb; }

        // phase 1: cheb einsum (3 mats, Tx2 folded) + residual 1x1, contraction over f
        for (int f = 0; f < F_IN; ++f) {
            float wa = Wabc[f * 64 + co];
            float wb = Wabc[2048 + f * 64 + co];
            float wc = Wabc[4096 + f * 64 + co];
            float wr = rWt[f * 64 + co];
#pragma unroll
            for (int q = 0; q < 4; ++q) {
                float4 xv = x4[f * 4 + q];
                float4 av = a4[f * 4 + q];
                float4 bv = b4[f * 4 + q];
                acc[q*4+0] = fmaf(wa, xv.x, fmaf(wb, av.x, fmaf(wc, bv.x, acc[q*4+0])));
                acc[q*4+1] = fmaf(wa, xv.y, fmaf(wb, av.y, fmaf(wc, bv.y, acc[q*4+1])));
                acc[q*4+2] = fmaf(wa, xv.z, fmaf(wb, av.z, fmaf(wc, bv.z, acc[q*4+2])));
                acc[q*4+3] = fmaf(wa, xv.w, fmaf(wb, av.w, fmaf(wc, bv.w, acc[q*4+3])));
                res[q*4+0] = fmaf(wr, xv.x, res[q*4+0]);
                res[q*4+1] = fmaf(wr, xv.y, res[q*4+1]);
                res[q*4+2] = fmaf(wr, xv.z, res[q*4+2]);
                res[q*4+3] = fmaf(wr, xv.w, res[q*4+3]);
            }
        }

        // relu -> sg tile in LDS (wave-private; same-wave DS ops are ordered, no barrier)
        sg[co][0] = 0.f; sg[co][17] = 0.f; sg[co][18] = 0.f; sg[co][19] = 0.f;
#pragma unroll
        for (int t = 0; t < 16; ++t) sg[co][t + 1] = fmaxf(acc[t], 0.f);

        // phase 2: temporal conv (kernel 3, pad 1), contraction over ci (broadcast LDS reads)
#pragma unroll
        for (int t = 0; t < 16; ++t) acc[t] = res[t] + tb;
        for (int ci = 0; ci < 64; ++ci) {
            float w0 = tWt[ci * 192 + co];
            float w1 = tWt[ci * 192 + 64 + co];
            float w2 = tWt[ci * 192 + 128 + co];
            const float4* srow = reinterpret_cast<const float4*>(sg[ci]);
            float4 s0 = srow[0], s1 = srow[1], s2 = srow[2], s3 = srow[3], s4 = srow[4];
            float s[20] = { s0.x,s0.y,s0.z,s0.w, s1.x,s1.y,s1.z,s1.w,
                            s2.x,s2.y,s2.z,s2.w, s3.x,s3.y,s3.z,s3.w,
                            s4.x,s4.y,s4.z,s4.w };
#pragma unroll
            for (int t = 0; t < 16; ++t)
                acc[t] = fmaf(w0, s[t], fmaf(w1, s[t + 1], fmaf(w2, s[t + 2], acc[t])));
        }

        // relu + LayerNorm over channels (64 = wave), write transposed (b,n,co,t)
        float z[16];
#pragma unroll
        for (int t = 0; t < 16; ++t) {
            float zz = fmaxf(acc[t], 0.f);
            float s1 = zz, s2 = zz * zz;
#pragma unroll
            for (int off = 32; off >= 1; off >>= 1) {
                s1 += __shfl_xor(s1, off);
                s2 += __shfl_xor(s2, off);
            }
            float mu  = s1 * (1.0f / 64.0f);
            float var = s2 * (1.0f / 64.0f) - mu * mu;
            z[t] = (zz - mu) * rsqrtf(var + 1e-5f) * g + bb;
        }
        float4* o4 = reinterpret_cast<float4*>(out + (size_t)item * 1024 + co * 16);
        o4[0] = make_float4(z[0],  z[1],  z[2],  z[3]);
        o4[1] = make_float4(z[4],  z[5],  z[6],  z[7]);
        o4[2] = make_float4(z[8],  z[9],  z[10], z[11]);
        o4[3] = make_float4(z[12], z[13], z[14], z[15]);
    }
}

extern "C" void kernel_launch(void* const* d_in, const int* in_sizes, int n_in,
                              void* d_out, int out_size, void* d_ws, size_t ws_size,
                              hipStream_t stream) {
    const float* x      = (const float*)d_in[0];
    const int*   ei     = (const int*)d_in[1];
    const float* cheb_W = (const float*)d_in[2];
    const float* cheb_b = (const float*)d_in[3];
    const float* time_W = (const float*)d_in[4];
    const float* time_b = (const float*)d_in[5];
    const float* res_W  = (const float*)d_in[6];
    const float* res_b  = (const float*)d_in[7];
    const float* ln_g   = (const float*)d_in[8];
    const float* ln_b   = (const float*)d_in[9];
    float* out = (float*)d_out;

    const int N = in_sizes[0] / (2 * F_IN * TT);   // B=2
    const int E = in_sizes[1] / 2;
    const int* row = ei;
    const int* col = ei + E;

    // workspace carve-out (256B aligned)
    char* w = (char*)d_ws;
    size_t off = 0;
    auto carve = [&](size_t bytes) { off = (off + 255) & ~(size_t)255; size_t o = off; off += bytes; return o; };
    float* deg    = (float*)(w + carve((size_t)N * 4));
    int*   cnt    = (int*)  (w + carve((size_t)N * 4));
    int*   rowptr = (int*)  (w + carve((size_t)(N + 1) * 4));
    int*   pos    = (int*)  (w + carve((size_t)E * 4));
    int*   srcs   = (int*)  (w + carve((size_t)E * 4));
    float* wsort  = (float*)(w + carve((size_t)E * 4));
    float* Wabc   = (float*)(w + carve(3 * 32 * 64 * 4));
    float* tWt    = (float*)(w + carve(64 * 3 * 64 * 4));
    float* rWt    = (float*)(w + carve(32 * 64 * 4));
    float* P1     = (float*)(w + carve((size_t)2 * N * FTN * 4));
    float* P2     = (float*)(w + carve((size_t)2 * N * FTN * 4));
    (void)ws_size; (void)n_in; (void)out_size;

    hipMemsetAsync(deg, 0, (size_t)N * 4, stream);
    hipMemsetAsync(cnt, 0, (size_t)N * 4, stream);

    int eb = (E + 255) / 256;
    k_edge1<<<eb, 256, 0, stream>>>(row, col, deg, cnt, pos, E);
    k_scan<<<1, 1024, 0, stream>>>(cnt, rowptr, N);
    k_fill<<<eb, 256, 0, stream>>>(row, col, deg, rowptr, pos, srcs, wsort, E);
    k_prop<<<N, 256, 0, stream>>>(x,  P1, rowptr, srcs, wsort, N);
    k_prop<<<N, 256, 0, stream>>>(P1, P2, rowptr, srcs, wsort, N);
    k_prep<<<48, 256, 0, stream>>>(cheb_W, time_W, res_W, Wabc, tWt, rWt);

    int items  = 2 * N;
    int blocks = (items + WPB - 1) / WPB;   // 4 waves/block, 1 item/wave
    k_fused<<<blocks, 64 * WPB, 0, stream>>>(x, P1, P2, Wabc, rWt, tWt,
                                             cheb_b, time_b, res_b, ln_g, ln_b, out, N);
}

// Round 4
// 585.241 us; speedup vs baseline: 1.2283x; 1.1107x over previous
//
#include <hip/hip_runtime.h>

// MSTGCN block, MI355X.
//  R2: 256-thread k_fused blocks (occupancy 24->32%).
//  R3: phase-1 inputs staged via coalesced float4 -> wave-private LDS; phase 1
//      reads broadcast ds_read_b128 (was 384 broadcast GLOBAL loads/item = the
//      latency stall; now 6 coalesced loads/item). sg tile overlays staging.
//      k_prop unrolled x4.

#define F_IN 32
#define TT   16
#define CCH  64
#define FTN  512   // F_IN*TT floats per (b,n)
#define WPB  4     // waves per block in k_fused
#define WSTR 1600  // per-wave LDS floats (staging 1536 used, sg overlay 1280)

__global__ void k_edge1(const int* __restrict__ row, const int* __restrict__ col,
                        float* __restrict__ deg, int* __restrict__ cnt,
                        int* __restrict__ pos, int E) {
    int i = blockIdx.x * 256 + threadIdx.x;
    if (i < E) {
        atomicAdd(&deg[row[i]], 1.0f);
        pos[i] = atomicAdd(&cnt[col[i]], 1);
    }
}

__global__ void k_scan(const int* __restrict__ cnt, int* __restrict__ rowptr, int n) {
    __shared__ int sdata[1024];
    int tid = threadIdx.x;
    int run = 0;
    for (int base = 0; base < n; base += 1024) {
        int v = (base + tid < n) ? cnt[base + tid] : 0;
        sdata[tid] = v;
        __syncthreads();
        for (int off = 1; off < 1024; off <<= 1) {
            int add = (tid >= off) ? sdata[tid - off] : 0;
            __syncthreads();
            sdata[tid] += add;
            __syncthreads();
        }
        int incl  = sdata[tid];
        int total = sdata[1023];
        if (base + tid < n) rowptr[base + tid] = run + incl - v;
        run += total;
        __syncthreads();
    }
    if (tid == 0) rowptr[n] = run;
}

__global__ void k_fill(const int* __restrict__ row, const int* __restrict__ col,
                       const float* __restrict__ deg, const int* __restrict__ rowptr,
                       const int* __restrict__ pos, int* __restrict__ srcs,
                       float* __restrict__ wsort, int E) {
    int i = blockIdx.x * 256 + threadIdx.x;
    if (i < E) {
        int r = row[i], c = col[i];
        float dr = deg[r], dc = deg[c];
        float w = 0.0f;
        if (dr > 0.0f && dc > 0.0f) w = -(rsqrtf(dr) * rsqrtf(dc));
        int slot = rowptr[c] + pos[i];
        srcs[slot]  = r;
        wsort[slot] = w;
    }
}

// Gather prop: one block per destination node. 256 threads x float4 = full
// B*F*T row of one source per iteration. 4-edge unroll for MLP. No atomics.
__global__ void k_prop(const float* __restrict__ zin, float* __restrict__ zout,
                       const int* __restrict__ rowptr, const int* __restrict__ srcs,
                       const float* __restrict__ wsort, int N) {
    int n   = blockIdx.x;
    int tid = threadIdx.x;                 // 0..255
    int beg = rowptr[n], end = rowptr[n + 1];
    const size_t bstride = (size_t)N * FTN;
    const size_t eoff = (size_t)(tid >> 7) * bstride + (size_t)(tid & 127) * 4;

    float4 a = make_float4(0.f, 0.f, 0.f, 0.f);
    int j = beg;
    for (; j + 3 < end; j += 4) {
        int   s0 = srcs[j],  s1 = srcs[j + 1], s2 = srcs[j + 2], s3 = srcs[j + 3];
        float w0 = wsort[j], w1 = wsort[j + 1], w2 = wsort[j + 2], w3 = wsort[j + 3];
        float4 v0 = *reinterpret_cast<const float4*>(zin + (size_t)s0 * FTN + eoff);
        float4 v1 = *reinterpret_cast<const float4*>(zin + (size_t)s1 * FTN + eoff);
        float4 v2 = *reinterpret_cast<const float4*>(zin + (size_t)s2 * FTN + eoff);
        float4 v3 = *reinterpret_cast<const float4*>(zin + (size_t)s3 * FTN + eoff);
        a.x = fmaf(w0, v0.x, fmaf(w1, v1.x, fmaf(w2, v2.x, fmaf(w3, v3.x, a.x))));
        a.y = fmaf(w0, v0.y, fmaf(w1, v1.y, fmaf(w2, v2.y, fmaf(w3, v3.y, a.y))));
        a.z = fmaf(w0, v0.z, fmaf(w1, v1.z, fmaf(w2, v2.z, fmaf(w3, v3.z, a.z))));
        a.w = fmaf(w0, v0.w, fmaf(w1, v1.w, fmaf(w2, v2.w, fmaf(w3, v3.w, a.w))));
    }
    for (; j < end; ++j) {
        int   s0 = srcs[j];
        float w0 = wsort[j];
        float4 v0 = *reinterpret_cast<const float4*>(zin + (size_t)s0 * FTN + eoff);
        a.x = fmaf(w0, v0.x, a.x);
        a.y = fmaf(w0, v0.y, a.y);
        a.z = fmaf(w0, v0.z, a.z);
        a.w = fmaf(w0, v0.w, a.w);
    }
    *reinterpret_cast<float4*>(zout + (size_t)n * FTN + eoff) = a;
}

// Weight prep: Wabc[3][32][64] (f,co), tWt[64][3][64] (ci,dt,co), rWt[32][64] (f,co)
__global__ void k_prep(const float* __restrict__ cheb_W, const float* __restrict__ time_W,
                       const float* __restrict__ res_W,
                       float* __restrict__ Wabc, float* __restrict__ tWt, float* __restrict__ rWt) {
    int i = blockIdx.x * 256 + threadIdx.x;
    if (i < F_IN * 64) {
        int f = i >> 6, o = i & 63;
        float w0 = cheb_W[(0 * F_IN + f) * 64 + o];
        float w1 = cheb_W[(1 * F_IN + f) * 64 + o];
        float w2 = cheb_W[(2 * F_IN + f) * 64 + o];
        Wabc[i]          = w0 - w2;
        Wabc[2048 + i]   = w1;
        Wabc[4096 + i]   = 2.0f * w2;
        rWt[i] = res_W[o * F_IN + f];
    }
    if (i < 64 * 3 * 64) {
        int ci = i / 192, r = i % 192, dt = r >> 6, co = r & 63;
        tWt[i] = time_W[(co * 64 + ci) * 3 + dt];
    }
}

// Fused per-(b,n) kernel. 256 threads = 4 waves; each wave owns one item (b,n).
// lane = output channel. Inputs staged coalesced into wave-private LDS; phase-1
// consumes them as broadcast ds_read_b128. sg tile overlays the staging region
// (staging fully consumed into acc/res registers before sg writes; same-wave
// LDS ops are in program order, so no barrier needed anywhere).
__global__ __launch_bounds__(256) void k_fused(
        const float* __restrict__ x, const float* __restrict__ P1, const float* __restrict__ P2,
        const float* __restrict__ Wabc, const float* __restrict__ rWt, const float* __restrict__ tWt,
        const float* __restrict__ cheb_b, const float* __restrict__ time_b,
        const float* __restrict__ res_b, const float* __restrict__ ln_g,
        const float* __restrict__ ln_b, float* __restrict__ out, int N) {
    __shared__ float smem[WPB * WSTR];
    int lane = threadIdx.x & 63;
    int wib  = threadIdx.x >> 6;
    int co   = lane;
    float chb = cheb_b[co], tb = time_b[co], rb = res_b[co];
    float lng = ln_g[co],   lnb = ln_b[co];
    float*  st = smem + wib * WSTR;
    float4* s4 = reinterpret_cast<float4*>(st);   // [0:128)=x, [128:256)=P1, [256:384)=P2

    int gw = blockIdx.x * WPB + wib;
    int nw = gridDim.x * WPB;
    int nitems = 2 * N;
    const size_t bstride = (size_t)N * FTN;

    for (int item = gw; item < nitems; item += nw) {
        int b = (item >= N) ? 1 : 0;
        int n = item - b * N;
        const float4* x4 = reinterpret_cast<const float4*>(x  + b * bstride + (size_t)n * FTN);
        const float4* a4 = reinterpret_cast<const float4*>(P1 + b * bstride + (size_t)n * FTN);
        const float4* b4 = reinterpret_cast<const float4*>(P2 + b * bstride + (size_t)n * FTN);

        // coalesced stage: 6 x (64 lanes x 16 B) = x,P1,P2 rows into LDS
        float4 xv0 = x4[lane], xv1 = x4[64 + lane];
        float4 av0 = a4[lane], av1 = a4[64 + lane];
        float4 bv0 = b4[lane], bv1 = b4[64 + lane];
        s4[lane]       = xv0;  s4[64 + lane]  = xv1;
        s4[128 + lane] = av0;  s4[192 + lane] = av1;
        s4[256 + lane] = bv0;  s4[320 + lane] = bv1;

        float acc[16], res[16];
#pragma unroll
        for (int t = 0; t < 16; ++t) { acc[t] = chb; res[t] = rb; }

        // phase 1: cheb einsum (3 mats, Tx2 folded) + residual 1x1, contraction over f
        for (int f = 0; f < F_IN; ++f) {
            float wa = Wabc[f * 64 + co];
            float wb = Wabc[2048 + f * 64 + co];
            float wc = Wabc[4096 + f * 64 + co];
            float wr = rWt[f * 64 + co];
#pragma unroll
            for (int q = 0; q < 4; ++q) {
                float4 xv = s4[f * 4 + q];          // broadcast ds_read_b128
                float4 av = s4[128 + f * 4 + q];
                float4 bv = s4[256 + f * 4 + q];
                acc[q*4+0] = fmaf(wa, xv.x, fmaf(wb, av.x, fmaf(wc, bv.x, acc[q*4+0])));
                acc[q*4+1] = fmaf(wa, xv.y, fmaf(wb, av.y, fmaf(wc, bv.y, acc[q*4+1])));
                acc[q*4+2] = fmaf(wa, xv.z, fmaf(wb, av.z, fmaf(wc, bv.z, acc[q*4+2])));
                acc[q*4+3] = fmaf(wa, xv.w, fmaf(wb, av.w, fmaf(wc, bv.w, acc[q*4+3])));
                res[q*4+0] = fmaf(wr, xv.x, res[q*4+0]);
                res[q*4+1] = fmaf(wr, xv.y, res[q*4+1]);
                res[q*4+2] = fmaf(wr, xv.z, res[q*4+2]);
                res[q*4+3] = fmaf(wr, xv.w, res[q*4+3]);
            }
        }

        // relu -> sg tile (overlays staging region; stride 20 floats, 16B-aligned rows)
        st[co * 20 + 0] = 0.f; st[co * 20 + 17] = 0.f;
        st[co * 20 + 18] = 0.f; st[co * 20 + 19] = 0.f;
#pragma unroll
        for (int t = 0; t < 16; ++t) st[co * 20 + t + 1] = fmaxf(acc[t], 0.f);

        // phase 2: temporal conv (kernel 3, pad 1), contraction over ci
#pragma unroll
        for (int t = 0; t < 16; ++t) acc[t] = res[t] + tb;
        for (int ci = 0; ci < 64; ++ci) {
            float w0 = tWt[ci * 192 + co];
            float w1 = tWt[ci * 192 + 64 + co];
            float w2 = tWt[ci * 192 + 128 + co];
            const float4* srow = reinterpret_cast<const float4*>(st + ci * 20);
            float4 s0 = srow[0], s1 = srow[1], s2 = srow[2], s3 = srow[3], s4v = srow[4];
            float s[20] = { s0.x,s0.y,s0.z,s0.w, s1.x,s1.y,s1.z,s1.w,
                            s2.x,s2.y,s2.z,s2.w, s3.x,s3.y,s3.z,s3.w,
                            s4v.x,s4v.y,s4v.z,s4v.w };
#pragma unroll
            for (int t = 0; t < 16; ++t)
                acc[t] = fmaf(w0, s[t], fmaf(w1, s[t + 1], fmaf(w2, s[t + 2], acc[t])));
        }

        // relu + LayerNorm over channels (64 = wave), write transposed (b,n,co,t)
        float z[16];
#pragma unroll
        for (int t = 0; t < 16; ++t) {
            float zz = fmaxf(acc[t], 0.f);
            float p1 = zz, p2 = zz * zz;
#pragma unroll
            for (int off = 32; off >= 1; off >>= 1) {
                p1 += __shfl_xor(p1, off);
                p2 += __shfl_xor(p2, off);
            }
            float mu  = p1 * (1.0f / 64.0f);
            float var = p2 * (1.0f / 64.0f) - mu * mu;
            z[t] = (zz - mu) * rsqrtf(var + 1e-5f) * lng + lnb;
        }
        float4* o4 = reinterpret_cast<float4*>(out + (size_t)item * 1024 + co * 16);
        o4[0] = make_float4(z[0],  z[1],  z[2],  z[3]);
        o4[1] = make_float4(z[4],  z[5],  z[6],  z[7]);
        o4[2] = make_float4(z[8],  z[9],  z[10], z[11]);
        o4[3] = make_float4(z[12], z[13], z[14], z[15]);
    }
}

extern "C" void kernel_launch(void* const* d_in, const int* in_sizes, int n_in,
                              void* d_out, int out_size, void* d_ws, size_t ws_size,
                              hipStream_t stream) {
    const float* x      = (const float*)d_in[0];
    const int*   ei     = (const int*)d_in[1];
    const float* cheb_W = (const float*)d_in[2];
    const float* cheb_b = (const float*)d_in[3];
    const float* time_W = (const float*)d_in[4];
    const float* time_b = (const float*)d_in[5];
    const float* res_W  = (const float*)d_in[6];
    const float* res_b  = (const float*)d_in[7];
    const float* ln_g   = (const float*)d_in[8];
    const float* ln_b   = (const float*)d_in[9];
    float* out = (float*)d_out;

    const int N = in_sizes[0] / (2 * F_IN * TT);   // B=2
    const int E = in_sizes[1] / 2;
    const int* row = ei;
    const int* col = ei + E;

    // workspace carve-out (256B aligned)
    char* w = (char*)d_ws;
    size_t off = 0;
    auto carve = [&](size_t bytes) { off = (off + 255) & ~(size_t)255; size_t o = off; off += bytes; return o; };
    float* deg    = (float*)(w + carve((size_t)N * 4));
    int*   cnt    = (int*)  (w + carve((size_t)N * 4));
    int*   rowptr = (int*)  (w + carve((size_t)(N + 1) * 4));
    int*   pos    = (int*)  (w + carve((size_t)E * 4));
    int*   srcs   = (int*)  (w + carve((size_t)E * 4));
    float* wsort  = (float*)(w + carve((size_t)E * 4));
    float* Wabc   = (float*)(w + carve(3 * 32 * 64 * 4));
    float* tWt    = (float*)(w + carve(64 * 3 * 64 * 4));
    float* rWt    = (float*)(w + carve(32 * 64 * 4));
    float* P1     = (float*)(w + carve((size_t)2 * N * FTN * 4));
    float* P2     = (float*)(w + carve((size_t)2 * N * FTN * 4));
    (void)ws_size; (void)n_in; (void)out_size;

    hipMemsetAsync(deg, 0, (size_t)N * 4, stream);
    hipMemsetAsync(cnt, 0, (size_t)N * 4, stream);

    int eb = (E + 255) / 256;
    k_edge1<<<eb, 256, 0, stream>>>(row, col, deg, cnt, pos, E);
    k_scan<<<1, 1024, 0, stream>>>(cnt, rowptr, N);
    k_fill<<<eb, 256, 0, stream>>>(row, col, deg, rowptr, pos, srcs, wsort, E);
    k_prop<<<N, 256, 0, stream>>>(x,  P1, rowptr, srcs, wsort, N);
    k_prop<<<N, 256, 0, stream>>>(P1, P2, rowptr, srcs, wsort, N);
    k_prep<<<48, 256, 0, stream>>>(cheb_W, time_W, res_W, Wabc, tWt, rWt);

    int items  = 2 * N;
    int blocks = (items + WPB - 1) / WPB;   // 4 waves/block, 1 item/wave
    k_fused<<<blocks, 64 * WPB, 0, stream>>>(x, P1, P2, Wabc, rWt, tWt,
                                             cheb_b, time_b, res_b, ln_g, ln_b, out, N);
}

// Round 5
// 584.160 us; speedup vs baseline: 1.2306x; 1.0019x over previous
//
#include <hip/hip_runtime.h>

// MSTGCN block, MI355X.
//  R2: 256-thread k_fused blocks (occupancy 24->32%).
//  R3: phase-1 inputs staged coalesced -> wave-private LDS (broadcast ds_read_b128).
//  R4: weights packed as float4 rows -> one global_load_dwordx4 per loop step
//      (was 320 scalar dword loads/item = the diagnosed latency stall; now 96).

#define F_IN 32
#define TT   16
#define CCH  64
#define FTN  512   // F_IN*TT floats per (b,n)
#define WPB  4     // waves per block in k_fused
#define WSTR 1600  // per-wave LDS floats (staging 1536 used, sg overlay 1280)

__global__ void k_edge1(const int* __restrict__ row, const int* __restrict__ col,
                        float* __restrict__ deg, int* __restrict__ cnt,
                        int* __restrict__ pos, int E) {
    int i = blockIdx.x * 256 + threadIdx.x;
    if (i < E) {
        atomicAdd(&deg[row[i]], 1.0f);
        pos[i] = atomicAdd(&cnt[col[i]], 1);
    }
}

__global__ void k_scan(const int* __restrict__ cnt, int* __restrict__ rowptr, int n) {
    __shared__ int sdata[1024];
    int tid = threadIdx.x;
    int run = 0;
    for (int base = 0; base < n; base += 1024) {
        int v = (base + tid < n) ? cnt[base + tid] : 0;
        sdata[tid] = v;
        __syncthreads();
        for (int off = 1; off < 1024; off <<= 1) {
            int add = (tid >= off) ? sdata[tid - off] : 0;
            __syncthreads();
            sdata[tid] += add;
            __syncthreads();
        }
        int incl  = sdata[tid];
        int total = sdata[1023];
        if (base + tid < n) rowptr[base + tid] = run + incl - v;
        run += total;
        __syncthreads();
    }
    if (tid == 0) rowptr[n] = run;
}

__global__ void k_fill(const int* __restrict__ row, const int* __restrict__ col,
                       const float* __restrict__ deg, const int* __restrict__ rowptr,
                       const int* __restrict__ pos, int* __restrict__ srcs,
                       float* __restrict__ wsort, int E) {
    int i = blockIdx.x * 256 + threadIdx.x;
    if (i < E) {
        int r = row[i], c = col[i];
        float dr = deg[r], dc = deg[c];
        float w = 0.0f;
        if (dr > 0.0f && dc > 0.0f) w = -(rsqrtf(dr) * rsqrtf(dc));
        int slot = rowptr[c] + pos[i];
        srcs[slot]  = r;
        wsort[slot] = w;
    }
}

// Gather prop: one block per destination node. 256 threads x float4 = full
// B*F*T row of one source per iteration. 4-edge unroll for MLP. No atomics.
__global__ void k_prop(const float* __restrict__ zin, float* __restrict__ zout,
                       const int* __restrict__ rowptr, const int* __restrict__ srcs,
                       const float* __restrict__ wsort, int N) {
    int n   = blockIdx.x;
    int tid = threadIdx.x;                 // 0..255
    int beg = rowptr[n], end = rowptr[n + 1];
    const size_t bstride = (size_t)N * FTN;
    const size_t eoff = (size_t)(tid >> 7) * bstride + (size_t)(tid & 127) * 4;

    float4 a = make_float4(0.f, 0.f, 0.f, 0.f);
    int j = beg;
    for (; j + 3 < end; j += 4) {
        int   s0 = srcs[j],  s1 = srcs[j + 1], s2 = srcs[j + 2], s3 = srcs[j + 3];
        float w0 = wsort[j], w1 = wsort[j + 1], w2 = wsort[j + 2], w3 = wsort[j + 3];
        float4 v0 = *reinterpret_cast<const float4*>(zin + (size_t)s0 * FTN + eoff);
        float4 v1 = *reinterpret_cast<const float4*>(zin + (size_t)s1 * FTN + eoff);
        float4 v2 = *reinterpret_cast<const float4*>(zin + (size_t)s2 * FTN + eoff);
        float4 v3 = *reinterpret_cast<const float4*>(zin + (size_t)s3 * FTN + eoff);
        a.x = fmaf(w0, v0.x, fmaf(w1, v1.x, fmaf(w2, v2.x, fmaf(w3, v3.x, a.x))));
        a.y = fmaf(w0, v0.y, fmaf(w1, v1.y, fmaf(w2, v2.y, fmaf(w3, v3.y, a.y))));
        a.z = fmaf(w0, v0.z, fmaf(w1, v1.z, fmaf(w2, v2.z, fmaf(w3, v3.z, a.z))));
        a.w = fmaf(w0, v0.w, fmaf(w1, v1.w, fmaf(w2, v2.w, fmaf(w3, v3.w, a.w))));
    }
    for (; j < end; ++j) {
        int   s0 = srcs[j];
        float w0 = wsort[j];
        float4 v0 = *reinterpret_cast<const float4*>(zin + (size_t)s0 * FTN + eoff);
        a.x = fmaf(w0, v0.x, a.x);
        a.y = fmaf(w0, v0.y, a.y);
        a.z = fmaf(w0, v0.z, a.z);
        a.w = fmaf(w0, v0.w, a.w);
    }
    *reinterpret_cast<float4*>(zout + (size_t)n * FTN + eoff) = a;
}

// Weight prep (packed float4 rows):
//   pW4[f][co] = { W0-W2, W1, 2*W2, resW }   (32*64 float4)
//   pT4[ci][co] = { tw_dt0, tw_dt1, tw_dt2, 0 }  (64*64 float4)
__global__ void k_prep(const float* __restrict__ cheb_W, const float* __restrict__ time_W,
                       const float* __restrict__ res_W,
                       float4* __restrict__ pW4, float4* __restrict__ pT4) {
    int i = blockIdx.x * 256 + threadIdx.x;
    if (i < F_IN * 64) {
        int f = i >> 6, o = i & 63;
        float w0 = cheb_W[(0 * F_IN + f) * 64 + o];
        float w1 = cheb_W[(1 * F_IN + f) * 64 + o];
        float w2 = cheb_W[(2 * F_IN + f) * 64 + o];
        pW4[i] = make_float4(w0 - w2, w1, 2.0f * w2, res_W[o * F_IN + f]);
    }
    if (i < 64 * 64) {
        int ci = i >> 6, co = i & 63;
        pT4[i] = make_float4(time_W[(co * 64 + ci) * 3 + 0],
                             time_W[(co * 64 + ci) * 3 + 1],
                             time_W[(co * 64 + ci) * 3 + 2], 0.0f);
    }
}

// Fused per-(b,n) kernel. 256 threads = 4 waves; each wave owns one item (b,n).
// lane = output channel. Inputs staged coalesced into wave-private LDS; phase-1
// consumes them as broadcast ds_read_b128. Weights: one dwordx4 per loop step.
__global__ __launch_bounds__(256) void k_fused(
        const float* __restrict__ x, const float* __restrict__ P1, const float* __restrict__ P2,
        const float4* __restrict__ pW4, const float4* __restrict__ pT4,
        const float* __restrict__ cheb_b, const float* __restrict__ time_b,
        const float* __restrict__ res_b, const float* __restrict__ ln_g,
        const float* __restrict__ ln_b, float* __restrict__ out, int N) {
    __shared__ float smem[WPB * WSTR];
    int lane = threadIdx.x & 63;
    int wib  = threadIdx.x >> 6;
    int co   = lane;
    float chb = cheb_b[co], tb = time_b[co], rb = res_b[co];
    float lng = ln_g[co],   lnb = ln_b[co];
    float*  st = smem + wib * WSTR;
    float4* s4 = reinterpret_cast<float4*>(st);   // [0:128)=x, [128:256)=P1, [256:384)=P2

    int gw = blockIdx.x * WPB + wib;
    int nw = gridDim.x * WPB;
    int nitems = 2 * N;
    const size_t bstride = (size_t)N * FTN;

    for (int item = gw; item < nitems; item += nw) {
        int b = (item >= N) ? 1 : 0;
        int n = item - b * N;
        const float4* x4 = reinterpret_cast<const float4*>(x  + b * bstride + (size_t)n * FTN);
        const float4* a4 = reinterpret_cast<const float4*>(P1 + b * bstride + (size_t)n * FTN);
        const float4* b4 = reinterpret_cast<const float4*>(P2 + b * bstride + (size_t)n * FTN);

        // coalesced stage: 6 x (64 lanes x 16 B) = x,P1,P2 rows into LDS
        float4 xv0 = x4[lane], xv1 = x4[64 + lane];
        float4 av0 = a4[lane], av1 = a4[64 + lane];
        float4 bv0 = b4[lane], bv1 = b4[64 + lane];
        s4[lane]       = xv0;  s4[64 + lane]  = xv1;
        s4[128 + lane] = av0;  s4[192 + lane] = av1;
        s4[256 + lane] = bv0;  s4[320 + lane] = bv1;

        float acc[16], res[16];
#pragma unroll
        for (int t = 0; t < 16; ++t) { acc[t] = chb; res[t] = rb; }

        // phase 1: cheb einsum (3 mats, Tx2 folded) + residual 1x1, contraction over f
        for (int f = 0; f < F_IN; ++f) {
            float4 wv = pW4[f * 64 + co];     // {wa, wb, wc, wr} one dwordx4
#pragma unroll
            for (int q = 0; q < 4; ++q) {
                float4 xv = s4[f * 4 + q];          // broadcast ds_read_b128
                float4 av = s4[128 + f * 4 + q];
                float4 bv = s4[256 + f * 4 + q];
                acc[q*4+0] = fmaf(wv.x, xv.x, fmaf(wv.y, av.x, fmaf(wv.z, bv.x, acc[q*4+0])));
                acc[q*4+1] = fmaf(wv.x, xv.y, fmaf(wv.y, av.y, fmaf(wv.z, bv.y, acc[q*4+1])));
                acc[q*4+2] = fmaf(wv.x, xv.z, fmaf(wv.y, av.z, fmaf(wv.z, bv.z, acc[q*4+2])));
                acc[q*4+3] = fmaf(wv.x, xv.w, fmaf(wv.y, av.w, fmaf(wv.z, bv.w, acc[q*4+3])));
                res[q*4+0] = fmaf(wv.w, xv.x, res[q*4+0]);
                res[q*4+1] = fmaf(wv.w, xv.y, res[q*4+1]);
                res[q*4+2] = fmaf(wv.w, xv.z, res[q*4+2]);
                res[q*4+3] = fmaf(wv.w, xv.w, res[q*4+3]);
            }
        }

        // relu -> sg tile (overlays staging region; stride 20 floats, 16B-aligned rows)
        st[co * 20 + 0] = 0.f; st[co * 20 + 17] = 0.f;
        st[co * 20 + 18] = 0.f; st[co * 20 + 19] = 0.f;
#pragma unroll
        for (int t = 0; t < 16; ++t) st[co * 20 + t + 1] = fmaxf(acc[t], 0.f);

        // phase 2: temporal conv (kernel 3, pad 1), contraction over ci
#pragma unroll
        for (int t = 0; t < 16; ++t) acc[t] = res[t] + tb;
        for (int ci = 0; ci < 64; ++ci) {
            float4 tv = pT4[ci * 64 + co];    // {w0, w1, w2, -} one dwordx4
            const float4* srow = reinterpret_cast<const float4*>(st + ci * 20);
            float4 s0 = srow[0], s1 = srow[1], s2 = srow[2], s3 = srow[3], s4v = srow[4];
            float s[20] = { s0.x,s0.y,s0.z,s0.w, s1.x,s1.y,s1.z,s1.w,
                            s2.x,s2.y,s2.z,s2.w, s3.x,s3.y,s3.z,s3.w,
                            s4v.x,s4v.y,s4v.z,s4v.w };
#pragma unroll
            for (int t = 0; t < 16; ++t)
                acc[t] = fmaf(tv.x, s[t], fmaf(tv.y, s[t + 1], fmaf(tv.z, s[t + 2], acc[t])));
        }

        // relu + LayerNorm over channels (64 = wave), write transposed (b,n,co,t)
        float z[16];
#pragma unroll
        for (int t = 0; t < 16; ++t) {
            float zz = fmaxf(acc[t], 0.f);
            float p1 = zz, p2 = zz * zz;
#pragma unroll
            for (int off = 32; off >= 1; off >>= 1) {
                p1 += __shfl_xor(p1, off);
                p2 += __shfl_xor(p2, off);
            }
            float mu  = p1 * (1.0f / 64.0f);
            float var = p2 * (1.0f / 64.0f) - mu * mu;
            z[t] = (zz - mu) * rsqrtf(var + 1e-5f) * lng + lnb;
        }
        float4* o4 = reinterpret_cast<float4*>(out + (size_t)item * 1024 + co * 16);
        o4[0] = make_float4(z[0],  z[1],  z[2],  z[3]);
        o4[1] = make_float4(z[4],  z[5],  z[6],  z[7]);
        o4[2] = make_float4(z[8],  z[9],  z[10], z[11]);
        o4[3] = make_float4(z[12], z[13], z[14], z[15]);
    }
}

extern "C" void kernel_launch(void* const* d_in, const int* in_sizes, int n_in,
                              void* d_out, int out_size, void* d_ws, size_t ws_size,
                              hipStream_t stream) {
    const float* x      = (const float*)d_in[0];
    const int*   ei     = (const int*)d_in[1];
    const float* cheb_W = (const float*)d_in[2];
    const float* cheb_b = (const float*)d_in[3];
    const float* time_W = (const float*)d_in[4];
    const float* time_b = (const float*)d_in[5];
    const float* res_W  = (const float*)d_in[6];
    const float* res_b  = (const float*)d_in[7];
    const float* ln_g   = (const float*)d_in[8];
    const float* ln_b   = (const float*)d_in[9];
    float* out = (float*)d_out;

    const int N = in_sizes[0] / (2 * F_IN * TT);   // B=2
    const int E = in_sizes[1] / 2;
    const int* row = ei;
    const int* col = ei + E;

    // workspace carve-out (256B aligned)
    char* w = (char*)d_ws;
    size_t off = 0;
    auto carve = [&](size_t bytes) { off = (off + 255) & ~(size_t)255; size_t o = off; off += bytes; return o; };
    float*  deg    = (float*) (w + carve((size_t)N * 4));
    int*    cnt    = (int*)   (w + carve((size_t)N * 4));
    int*    rowptr = (int*)   (w + carve((size_t)(N + 1) * 4));
    int*    pos    = (int*)   (w + carve((size_t)E * 4));
    int*    srcs   = (int*)   (w + carve((size_t)E * 4));
    float*  wsort  = (float*) (w + carve((size_t)E * 4));
    float4* pW4    = (float4*)(w + carve((size_t)F_IN * 64 * 16));
    float4* pT4    = (float4*)(w + carve((size_t)64 * 64 * 16));
    float*  P1     = (float*) (w + carve((size_t)2 * N * FTN * 4));
    float*  P2     = (float*) (w + carve((size_t)2 * N * FTN * 4));
    (void)ws_size; (void)n_in; (void)out_size;

    hipMemsetAsync(deg, 0, (size_t)N * 4, stream);
    hipMemsetAsync(cnt, 0, (size_t)N * 4, stream);

    int eb = (E + 255) / 256;
    k_edge1<<<eb, 256, 0, stream>>>(row, col, deg, cnt, pos, E);
    k_scan<<<1, 1024, 0, stream>>>(cnt, rowptr, N);
    k_fill<<<eb, 256, 0, stream>>>(row, col, deg, rowptr, pos, srcs, wsort, E);
    k_prop<<<N, 256, 0, stream>>>(x,  P1, rowptr, srcs, wsort, N);
    k_prop<<<N, 256, 0, stream>>>(P1, P2, rowptr, srcs, wsort, N);
    k_prep<<<16, 256, 0, stream>>>(cheb_W, time_W, res_W, pW4, pT4);

    int items  = 2 * N;
    int blocks = (items + WPB - 1) / WPB;   // 4 waves/block, 1 item/wave
    k_fused<<<blocks, 64 * WPB, 0, stream>>>(x, P1, P2, pW4, pT4,
                                             cheb_b, time_b, res_b, ln_g, ln_b, out, N);
}